// Round 1
// baseline (2930.414 us; speedup 1.0000x reference)
//
#include <hip/hip_runtime.h>
#include <hip/hip_bf16.h>

#define N_NODES 50000
#define N_EDGES 800000
#define DIM 128
#define NUM_GRAPHS 128
#define BN_EPS 1e-5f

// ---------------------------------------------------------------------------
// scatter-add: agg[dst[e]][c] += feat[src[e]][c]
// thread = (edge, 4-channel group); 32 threads per edge; float4 gather,
// 4 scalar f32 atomics. agg must be pre-zeroed.
// ---------------------------------------------------------------------------
__global__ __launch_bounds__(256)
void scatter_add_kernel(const float* __restrict__ feat,
                        const int* __restrict__ src,
                        const int* __restrict__ dst,
                        float* __restrict__ agg,
                        int n_edges)
{
    int tid = blockIdx.x * 256 + threadIdx.x;
    int e = tid >> 5;
    if (e >= n_edges) return;
    int c4 = (tid & 31) << 2;
    int s = src[e];
    int d = dst[e];
    float4 v = *reinterpret_cast<const float4*>(feat + (size_t)s * DIM + c4);
    float* p = agg + (size_t)d * DIM + c4;
    atomicAdd(p + 0, v.x);
    atomicAdd(p + 1, v.y);
    atomicAdd(p + 2, v.z);
    atomicAdd(p + 3, v.w);
}

// ---------------------------------------------------------------------------
// Fused GEMM: out = act( BN( (in0 [+ in1]) @ W + bias ) )
// W is 128x128 row-major (fan_in x fan_out). Block computes a 64-row x
// 64-col tile (col half chosen by blockIdx&1). 256 threads, 4x4 register
// tile each. IN tile (64x128, 32KB) and W half (128x64, 32KB) in LDS.
// ---------------------------------------------------------------------------
constexpr int TBM = 64;   // rows per block
constexpr int TBN = 64;   // cols per block (half of DIM)

template<bool ADD, bool HASBN, bool RELU>
__global__ __launch_bounds__(256)
void gemm_mlp_kernel(const float* __restrict__ in0,
                     const float* __restrict__ in1,
                     const float* __restrict__ W,
                     const float* __restrict__ bias,
                     const float* __restrict__ bng,
                     const float* __restrict__ bnb,
                     const float* __restrict__ bnm,
                     const float* __restrict__ bnv,
                     float* __restrict__ out,
                     int M)
{
    __shared__ float sIn[TBM * DIM];      // 32 KB
    __shared__ float sW[DIM * TBN];       // 32 KB

    const int t    = threadIdx.x;
    const int tile = blockIdx.x >> 1;
    const int half = blockIdx.x & 1;
    const int row0 = tile * TBM;

    // stage W half: 128 k-rows x 64 cols = 2048 float4, 8 per thread
    {
        const float* Wsrc = W + half * TBN;
        #pragma unroll
        for (int i = t; i < DIM * (TBN / 4); i += 256) {
            int k  = i >> 4;            // 16 float4 per k-row
            int c4 = (i & 15) << 2;
            float4 v = *reinterpret_cast<const float4*>(Wsrc + (size_t)k * DIM + c4);
            *reinterpret_cast<float4*>(&sW[k * TBN + c4]) = v;
        }
    }
    // stage IN tile: 64 rows x 128 = 2048 float4, 8 per thread
    {
        #pragma unroll
        for (int i = t; i < TBM * (DIM / 4); i += 256) {
            int r  = i >> 5;            // 32 float4 per row
            int c4 = (i & 31) << 2;
            int gr = row0 + r;
            float4 v = make_float4(0.f, 0.f, 0.f, 0.f);
            if (gr < M) {
                v = *reinterpret_cast<const float4*>(in0 + (size_t)gr * DIM + c4);
                if constexpr (ADD) {
                    float4 a = *reinterpret_cast<const float4*>(in1 + (size_t)gr * DIM + c4);
                    v.x += a.x; v.y += a.y; v.z += a.z; v.w += a.w;
                }
            }
            *reinterpret_cast<float4*>(&sIn[r * DIM + c4]) = v;
        }
    }
    __syncthreads();

    const int colg = t & 15;    // 16 col-groups * 4 cols
    const int rowg = t >> 4;    // 16 row-groups * 4 rows

    float acc[4][4] = {};

    #pragma unroll 2
    for (int k = 0; k < DIM; k += 4) {
        float4 a[4], b[4];
        #pragma unroll
        for (int i = 0; i < 4; ++i)
            a[i] = *reinterpret_cast<const float4*>(&sIn[(rowg * 4 + i) * DIM + k]);
        #pragma unroll
        for (int kk = 0; kk < 4; ++kk)
            b[kk] = *reinterpret_cast<const float4*>(&sW[(k + kk) * TBN + colg * 4]);
        #pragma unroll
        for (int i = 0; i < 4; ++i) {
            float av0 = a[i].x, av1 = a[i].y, av2 = a[i].z, av3 = a[i].w;
            acc[i][0] = fmaf(av0, b[0].x, acc[i][0]);
            acc[i][1] = fmaf(av0, b[0].y, acc[i][1]);
            acc[i][2] = fmaf(av0, b[0].z, acc[i][2]);
            acc[i][3] = fmaf(av0, b[0].w, acc[i][3]);
            acc[i][0] = fmaf(av1, b[1].x, acc[i][0]);
            acc[i][1] = fmaf(av1, b[1].y, acc[i][1]);
            acc[i][2] = fmaf(av1, b[1].z, acc[i][2]);
            acc[i][3] = fmaf(av1, b[1].w, acc[i][3]);
            acc[i][0] = fmaf(av2, b[2].x, acc[i][0]);
            acc[i][1] = fmaf(av2, b[2].y, acc[i][1]);
            acc[i][2] = fmaf(av2, b[2].z, acc[i][2]);
            acc[i][3] = fmaf(av2, b[2].w, acc[i][3]);
            acc[i][0] = fmaf(av3, b[3].x, acc[i][0]);
            acc[i][1] = fmaf(av3, b[3].y, acc[i][1]);
            acc[i][2] = fmaf(av3, b[3].z, acc[i][2]);
            acc[i][3] = fmaf(av3, b[3].w, acc[i][3]);
        }
    }

    // epilogue: bias (+BN) (+ReLU), write float4 per row
    const int gc0 = half * TBN + colg * 4;
    float sc[4], sh[4];
    #pragma unroll
    for (int j = 0; j < 4; ++j) {
        int c = gc0 + j;
        float bi = bias[c];
        if constexpr (HASBN) {
            float s = bng[c] * rsqrtf(bnv[c] + BN_EPS);
            sc[j] = s;
            sh[j] = (bi - bnm[c]) * s + bnb[c];
        } else {
            sc[j] = 1.f;
            sh[j] = bi;
        }
    }
    #pragma unroll
    for (int i = 0; i < 4; ++i) {
        int gr = row0 + rowg * 4 + i;
        if (gr < M) {
            float4 o;
            o.x = fmaf(acc[i][0], sc[0], sh[0]);
            o.y = fmaf(acc[i][1], sc[1], sh[1]);
            o.z = fmaf(acc[i][2], sc[2], sh[2]);
            o.w = fmaf(acc[i][3], sc[3], sh[3]);
            if constexpr (RELU) {
                o.x = fmaxf(o.x, 0.f);
                o.y = fmaxf(o.y, 0.f);
                o.z = fmaxf(o.z, 0.f);
                o.w = fmaxf(o.w, 0.f);
            }
            *reinterpret_cast<float4*>(out + (size_t)gr * DIM + gc0) = o;
        }
    }
}

// ---------------------------------------------------------------------------
// global_add_pool: one block per graph; batch is sorted, binary-search range.
// ---------------------------------------------------------------------------
__global__ __launch_bounds__(256)
void pool_kernel(const float* __restrict__ h,
                 const int* __restrict__ batch,
                 float* __restrict__ G,
                 int n_nodes)
{
    const int g = blockIdx.x;
    int lo = 0, hi = n_nodes;
    while (lo < hi) { int mid = (lo + hi) >> 1; if (batch[mid] < g) lo = mid + 1; else hi = mid; }
    const int start = lo;
    hi = n_nodes;
    while (lo < hi) { int mid = (lo + hi) >> 1; if (batch[mid] < g + 1) lo = mid + 1; else hi = mid; }
    const int end = lo;

    const int t  = threadIdx.x;
    const int c  = t & 127;
    const int rp = t >> 7;
    float acc = 0.f;
    for (int r = start + rp; r < end; r += 2)
        acc += h[(size_t)r * DIM + c];
    __shared__ float s[256];
    s[t] = acc;
    __syncthreads();
    if (t < 128)
        G[g * DIM + t] = s[t] + s[t + 128];
}

// ---------------------------------------------------------------------------
// head: G2 = relu(G @ lin1 + b1)   (128x128 @ 128x128)
// ---------------------------------------------------------------------------
__global__ __launch_bounds__(256)
void head1_kernel(const float* __restrict__ G,
                  const float* __restrict__ W,
                  const float* __restrict__ b,
                  float* __restrict__ G2)
{
    int o = blockIdx.x * 256 + threadIdx.x;   // 64 blocks -> 16384 outputs
    int r = o >> 7, c = o & 127;
    float acc = b[c];
    #pragma unroll 4
    for (int k = 0; k < DIM; ++k)
        acc = fmaf(G[r * DIM + k], W[k * DIM + c], acc);
    G2[o] = fmaxf(acc, 0.f);
}

// out = G2 @ lin2 + b2   (128x128 @ 128x2)
__global__ __launch_bounds__(256)
void head2_kernel(const float* __restrict__ G2,
                  const float* __restrict__ W,
                  const float* __restrict__ b,
                  float* __restrict__ out)
{
    int o = threadIdx.x;            // 256 outputs
    int r = o >> 1, c = o & 1;
    float acc = b[c];
    #pragma unroll 4
    for (int k = 0; k < DIM; ++k)
        acc = fmaf(G2[r * DIM + k], W[k * 2 + c], acc);
    out[o] = acc;
}

// ---------------------------------------------------------------------------
extern "C" void kernel_launch(void* const* d_in, const int* in_sizes, int n_in,
                              void* d_out, int out_size, void* d_ws, size_t ws_size,
                              hipStream_t stream)
{
    const float* x    = (const float*)d_in[0];
    const int*   ei   = (const int*)d_in[1];
    const int*   src  = ei;
    const int*   dst  = ei + N_EDGES;
    const int*   batch= (const int*)d_in[2];
    const float* w1_1 = (const float*)d_in[3];
    const float* b1_1 = (const float*)d_in[4];
    const float* bn1g = (const float*)d_in[5];
    const float* bn1b = (const float*)d_in[6];
    const float* bn1m = (const float*)d_in[7];
    const float* bn1v = (const float*)d_in[8];
    const float* w1_2 = (const float*)d_in[9];
    const float* b1_2 = (const float*)d_in[10];
    const float* w2_1 = (const float*)d_in[11];
    const float* b2_1 = (const float*)d_in[12];
    const float* bn2g = (const float*)d_in[13];
    const float* bn2b = (const float*)d_in[14];
    const float* bn2m = (const float*)d_in[15];
    const float* bn2v = (const float*)d_in[16];
    const float* w2_2 = (const float*)d_in[17];
    const float* b2_2 = (const float*)d_in[18];
    const float* lin1w= (const float*)d_in[19];
    const float* lin1b= (const float*)d_in[20];
    const float* lin2w= (const float*)d_in[21];
    const float* lin2b= (const float*)d_in[22];

    const size_t NBE = (size_t)N_NODES * DIM;      // 6.4M floats
    float* B0 = (float*)d_ws;                      // agg1 / t2-out / h2
    float* B1 = B0 + NBE;                          // t1 / t2
    float* B2 = B1 + NBE;                          // h1
    float* G  = B2 + NBE;                          // 128x128 pooled
    float* G2 = G + NUM_GRAPHS * DIM;              // head intermediate

    const int gemm_grid    = ((N_NODES + TBM - 1) / TBM) * 2;   // 1564
    const int scatter_grid = (N_EDGES * 32 + 255) / 256;        // 100000

    // ---- conv1 ----
    hipMemsetAsync(B0, 0, NBE * sizeof(float), stream);
    scatter_add_kernel<<<scatter_grid, 256, 0, stream>>>(x, src, dst, B0, N_EDGES);
    gemm_mlp_kernel<true, true, true><<<gemm_grid, 256, 0, stream>>>(
        x, B0, w1_1, b1_1, bn1g, bn1b, bn1m, bn1v, B1, N_NODES);
    gemm_mlp_kernel<false, false, true><<<gemm_grid, 256, 0, stream>>>(
        B1, nullptr, w1_2, b1_2, nullptr, nullptr, nullptr, nullptr, B2, N_NODES);

    // ---- conv2 ----
    hipMemsetAsync(B0, 0, NBE * sizeof(float), stream);
    scatter_add_kernel<<<scatter_grid, 256, 0, stream>>>(B2, src, dst, B0, N_EDGES);
    gemm_mlp_kernel<true, true, true><<<gemm_grid, 256, 0, stream>>>(
        B2, B0, w2_1, b2_1, bn2g, bn2b, bn2m, bn2v, B1, N_NODES);
    gemm_mlp_kernel<false, false, true><<<gemm_grid, 256, 0, stream>>>(
        B1, nullptr, w2_2, b2_2, nullptr, nullptr, nullptr, nullptr, B0, N_NODES);

    // ---- pool + head ----
    pool_kernel<<<NUM_GRAPHS, 256, 0, stream>>>(B0, batch, G, N_NODES);
    head1_kernel<<<64, 256, 0, stream>>>(G, lin1w, lin1b, G2);
    head2_kernel<<<1, 256, 0, stream>>>(G2, lin2w, lin2b, (float*)d_out);
}

// Round 2
// 455.589 us; speedup vs baseline: 6.4321x; 6.4321x over previous
//
#include <hip/hip_runtime.h>
#include <hip/hip_bf16.h>

#define N_NODES 50000
#define N_EDGES 800000
#define DIM 128
#define NUM_GRAPHS 128
#define BN_EPS 1e-5f

constexpr int CHUNK  = 512;
constexpr int NCHUNK = (N_NODES + CHUNK - 1) / CHUNK;   // 98

// ---------------------------------------------------------------------------
// CSR build: histogram of dst, exclusive scan -> rowptr, fill elist with src
// ---------------------------------------------------------------------------
__global__ __launch_bounds__(256)
void csr_hist_kernel(const int* __restrict__ dst, int* __restrict__ deg)
{
    int e = blockIdx.x * 256 + threadIdx.x;
    if (e < N_EDGES) atomicAdd(&deg[dst[e]], 1);
}

__global__ __launch_bounds__(256)
void csr_partial_kernel(const int* __restrict__ deg, int* __restrict__ partial)
{
    __shared__ int s[256];
    int blk = blockIdx.x;
    int t = threadIdx.x;
    int i0 = blk * CHUNK + t;
    int v = 0;
    if (i0 < N_NODES) v += deg[i0];
    if (i0 + 256 < N_NODES && t + 256 < CHUNK) v += deg[i0 + 256];
    s[t] = v;
    __syncthreads();
    for (int off = 128; off > 0; off >>= 1) {
        if (t < off) s[t] += s[t + off];
        __syncthreads();
    }
    if (t == 0) partial[blk] = s[0];
}

__global__ __launch_bounds__(64)
void csr_scanpart_kernel(int* __restrict__ partial)
{
    if (threadIdx.x == 0) {
        int run = 0;
        for (int i = 0; i < NCHUNK; ++i) {
            int v = partial[i];
            partial[i] = run;
            run += v;
        }
    }
}

__global__ __launch_bounds__(CHUNK)
void csr_rowptr_kernel(const int* __restrict__ deg,
                       const int* __restrict__ partial,
                       int* __restrict__ rowptr,
                       int* __restrict__ cursor)
{
    __shared__ int s[CHUNK];
    int t = threadIdx.x;
    int i = blockIdx.x * CHUNK + t;
    int v = (i < N_NODES) ? deg[i] : 0;
    s[t] = v;
    __syncthreads();
    // Hillis-Steele inclusive scan
    for (int off = 1; off < CHUNK; off <<= 1) {
        int add = (t >= off) ? s[t - off] : 0;
        __syncthreads();
        s[t] += add;
        __syncthreads();
    }
    if (i < N_NODES) {
        int excl = partial[blockIdx.x] + s[t] - v;
        rowptr[i] = excl;
        cursor[i] = excl;
    }
    if (blockIdx.x == 0 && t == 0) rowptr[N_NODES] = N_EDGES;
}

__global__ __launch_bounds__(256)
void csr_fill_kernel(const int* __restrict__ src,
                     const int* __restrict__ dst,
                     int* __restrict__ cursor,
                     int* __restrict__ elist)
{
    int e = blockIdx.x * 256 + threadIdx.x;
    if (e < N_EDGES) {
        int idx = atomicAdd(&cursor[dst[e]], 1);
        elist[idx] = src[e];
    }
}

// ---------------------------------------------------------------------------
// gather-aggregate, fused with the GIN "+x" term:
//   out[i][:] = addin[i][:] + sum_{e in CSR[i]} feat[elist[e]][:]
// 2 nodes per 256-thread block; thread owns one channel.
// ---------------------------------------------------------------------------
__global__ __launch_bounds__(256)
void gather_agg_kernel(const float* __restrict__ feat,
                       const float* __restrict__ addin,
                       const int* __restrict__ rowptr,
                       const int* __restrict__ elist,
                       float* __restrict__ out)
{
    int node = blockIdx.x * 2 + (threadIdx.x >> 7);
    int c    = threadIdx.x & 127;
    if (node >= N_NODES) return;
    int p = rowptr[node];
    const int e = rowptr[node + 1];
    float a0 = addin[(size_t)node * DIM + c];
    float a1 = 0.f, a2 = 0.f, a3 = 0.f;
    for (; p + 4 <= e; p += 4) {
        int s0 = elist[p], s1 = elist[p + 1], s2 = elist[p + 2], s3 = elist[p + 3];
        a0 += feat[(size_t)s0 * DIM + c];
        a1 += feat[(size_t)s1 * DIM + c];
        a2 += feat[(size_t)s2 * DIM + c];
        a3 += feat[(size_t)s3 * DIM + c];
    }
    for (; p < e; ++p)
        a0 += feat[(size_t)elist[p] * DIM + c];
    out[(size_t)node * DIM + c] = (a0 + a1) + (a2 + a3);
}

// ---------------------------------------------------------------------------
// Fused GEMM: out = act( BN( in0 @ W + bias ) )
// W is 128x128 row-major. Block = 64 rows x 64 cols, 256 threads, 4x4 rtile.
// ---------------------------------------------------------------------------
constexpr int TBM = 64;
constexpr int TBN = 64;

template<bool HASBN, bool RELU>
__global__ __launch_bounds__(256)
void gemm_mlp_kernel(const float* __restrict__ in0,
                     const float* __restrict__ W,
                     const float* __restrict__ bias,
                     const float* __restrict__ bng,
                     const float* __restrict__ bnb,
                     const float* __restrict__ bnm,
                     const float* __restrict__ bnv,
                     float* __restrict__ out,
                     int M)
{
    __shared__ float sIn[TBM * DIM];
    __shared__ float sW[DIM * TBN];

    const int t    = threadIdx.x;
    const int tile = blockIdx.x >> 1;
    const int half = blockIdx.x & 1;
    const int row0 = tile * TBM;

    {
        const float* Wsrc = W + half * TBN;
        #pragma unroll
        for (int i = t; i < DIM * (TBN / 4); i += 256) {
            int k  = i >> 4;
            int c4 = (i & 15) << 2;
            float4 v = *reinterpret_cast<const float4*>(Wsrc + (size_t)k * DIM + c4);
            *reinterpret_cast<float4*>(&sW[k * TBN + c4]) = v;
        }
    }
    {
        #pragma unroll
        for (int i = t; i < TBM * (DIM / 4); i += 256) {
            int r  = i >> 5;
            int c4 = (i & 31) << 2;
            int gr = row0 + r;
            float4 v = make_float4(0.f, 0.f, 0.f, 0.f);
            if (gr < M)
                v = *reinterpret_cast<const float4*>(in0 + (size_t)gr * DIM + c4);
            *reinterpret_cast<float4*>(&sIn[r * DIM + c4]) = v;
        }
    }
    __syncthreads();

    const int colg = t & 15;
    const int rowg = t >> 4;

    float acc[4][4] = {};

    #pragma unroll 2
    for (int k = 0; k < DIM; k += 4) {
        float4 a[4], b[4];
        #pragma unroll
        for (int i = 0; i < 4; ++i)
            a[i] = *reinterpret_cast<const float4*>(&sIn[(rowg * 4 + i) * DIM + k]);
        #pragma unroll
        for (int kk = 0; kk < 4; ++kk)
            b[kk] = *reinterpret_cast<const float4*>(&sW[(k + kk) * TBN + colg * 4]);
        #pragma unroll
        for (int i = 0; i < 4; ++i) {
            float av0 = a[i].x, av1 = a[i].y, av2 = a[i].z, av3 = a[i].w;
            acc[i][0] = fmaf(av0, b[0].x, acc[i][0]);
            acc[i][1] = fmaf(av0, b[0].y, acc[i][1]);
            acc[i][2] = fmaf(av0, b[0].z, acc[i][2]);
            acc[i][3] = fmaf(av0, b[0].w, acc[i][3]);
            acc[i][0] = fmaf(av1, b[1].x, acc[i][0]);
            acc[i][1] = fmaf(av1, b[1].y, acc[i][1]);
            acc[i][2] = fmaf(av1, b[1].z, acc[i][2]);
            acc[i][3] = fmaf(av1, b[1].w, acc[i][3]);
            acc[i][0] = fmaf(av2, b[2].x, acc[i][0]);
            acc[i][1] = fmaf(av2, b[2].y, acc[i][1]);
            acc[i][2] = fmaf(av2, b[2].z, acc[i][2]);
            acc[i][3] = fmaf(av2, b[2].w, acc[i][3]);
            acc[i][0] = fmaf(av3, b[3].x, acc[i][0]);
            acc[i][1] = fmaf(av3, b[3].y, acc[i][1]);
            acc[i][2] = fmaf(av3, b[3].z, acc[i][2]);
            acc[i][3] = fmaf(av3, b[3].w, acc[i][3]);
        }
    }

    const int gc0 = half * TBN + colg * 4;
    float sc[4], sh[4];
    #pragma unroll
    for (int j = 0; j < 4; ++j) {
        int c = gc0 + j;
        float bi = bias[c];
        if constexpr (HASBN) {
            float s = bng[c] * rsqrtf(bnv[c] + BN_EPS);
            sc[j] = s;
            sh[j] = (bi - bnm[c]) * s + bnb[c];
        } else {
            sc[j] = 1.f;
            sh[j] = bi;
        }
    }
    #pragma unroll
    for (int i = 0; i < 4; ++i) {
        int gr = row0 + rowg * 4 + i;
        if (gr < M) {
            float4 o;
            o.x = fmaf(acc[i][0], sc[0], sh[0]);
            o.y = fmaf(acc[i][1], sc[1], sh[1]);
            o.z = fmaf(acc[i][2], sc[2], sh[2]);
            o.w = fmaf(acc[i][3], sc[3], sh[3]);
            if constexpr (RELU) {
                o.x = fmaxf(o.x, 0.f);
                o.y = fmaxf(o.y, 0.f);
                o.z = fmaxf(o.z, 0.f);
                o.w = fmaxf(o.w, 0.f);
            }
            *reinterpret_cast<float4*>(out + (size_t)gr * DIM + gc0) = o;
        }
    }
}

// ---------------------------------------------------------------------------
__global__ __launch_bounds__(256)
void pool_kernel(const float* __restrict__ h,
                 const int* __restrict__ batch,
                 float* __restrict__ G,
                 int n_nodes)
{
    const int g = blockIdx.x;
    int lo = 0, hi = n_nodes;
    while (lo < hi) { int mid = (lo + hi) >> 1; if (batch[mid] < g) lo = mid + 1; else hi = mid; }
    const int start = lo;
    hi = n_nodes;
    while (lo < hi) { int mid = (lo + hi) >> 1; if (batch[mid] < g + 1) lo = mid + 1; else hi = mid; }
    const int end = lo;

    const int t  = threadIdx.x;
    const int c  = t & 127;
    const int rp = t >> 7;
    float acc = 0.f;
    for (int r = start + rp; r < end; r += 2)
        acc += h[(size_t)r * DIM + c];
    __shared__ float s[256];
    s[t] = acc;
    __syncthreads();
    if (t < 128)
        G[g * DIM + t] = s[t] + s[t + 128];
}

__global__ __launch_bounds__(256)
void head1_kernel(const float* __restrict__ G,
                  const float* __restrict__ W,
                  const float* __restrict__ b,
                  float* __restrict__ G2)
{
    int o = blockIdx.x * 256 + threadIdx.x;
    int r = o >> 7, c = o & 127;
    float acc = b[c];
    #pragma unroll 4
    for (int k = 0; k < DIM; ++k)
        acc = fmaf(G[r * DIM + k], W[k * DIM + c], acc);
    G2[o] = fmaxf(acc, 0.f);
}

__global__ __launch_bounds__(256)
void head2_kernel(const float* __restrict__ G2,
                  const float* __restrict__ W,
                  const float* __restrict__ b,
                  float* __restrict__ out)
{
    int o = threadIdx.x;
    int r = o >> 1, c = o & 1;
    float acc = b[c];
    #pragma unroll 4
    for (int k = 0; k < DIM; ++k)
        acc = fmaf(G2[r * DIM + k], W[k * 2 + c], acc);
    out[o] = acc;
}

// ---------------------------------------------------------------------------
extern "C" void kernel_launch(void* const* d_in, const int* in_sizes, int n_in,
                              void* d_out, int out_size, void* d_ws, size_t ws_size,
                              hipStream_t stream)
{
    const float* x    = (const float*)d_in[0];
    const int*   ei   = (const int*)d_in[1];
    const int*   src  = ei;
    const int*   dst  = ei + N_EDGES;
    const int*   batch= (const int*)d_in[2];
    const float* w1_1 = (const float*)d_in[3];
    const float* b1_1 = (const float*)d_in[4];
    const float* bn1g = (const float*)d_in[5];
    const float* bn1b = (const float*)d_in[6];
    const float* bn1m = (const float*)d_in[7];
    const float* bn1v = (const float*)d_in[8];
    const float* w1_2 = (const float*)d_in[9];
    const float* b1_2 = (const float*)d_in[10];
    const float* w2_1 = (const float*)d_in[11];
    const float* b2_1 = (const float*)d_in[12];
    const float* bn2g = (const float*)d_in[13];
    const float* bn2b = (const float*)d_in[14];
    const float* bn2m = (const float*)d_in[15];
    const float* bn2v = (const float*)d_in[16];
    const float* w2_2 = (const float*)d_in[17];
    const float* b2_2 = (const float*)d_in[18];
    const float* lin1w= (const float*)d_in[19];
    const float* lin1b= (const float*)d_in[20];
    const float* lin2w= (const float*)d_in[21];
    const float* lin2b= (const float*)d_in[22];

    const size_t NBE = (size_t)N_NODES * DIM;
    float* B0 = (float*)d_ws;
    float* B1 = B0 + NBE;
    float* B2 = B1 + NBE;
    float* G  = B2 + NBE;
    float* G2 = G + NUM_GRAPHS * DIM;
    int*   deg    = (int*)(G2 + NUM_GRAPHS * DIM);
    int*   rowptr = deg + N_NODES;           // N_NODES+1
    int*   cursor = rowptr + N_NODES + 1;
    int*   partial= cursor + N_NODES;        // NCHUNK
    int*   elist  = partial + NCHUNK + 2;    // N_EDGES

    const int gemm_grid   = ((N_NODES + TBM - 1) / TBM) * 2;   // 1564
    const int edge_grid   = (N_EDGES + 255) / 256;             // 3125
    const int gather_grid = (N_NODES + 1) / 2;                 // 25000

    // ---- CSR build (once; reused by both layers) ----
    hipMemsetAsync(deg, 0, N_NODES * sizeof(int), stream);
    csr_hist_kernel<<<edge_grid, 256, 0, stream>>>(dst, deg);
    csr_partial_kernel<<<NCHUNK, 256, 0, stream>>>(deg, partial);
    csr_scanpart_kernel<<<1, 64, 0, stream>>>(partial);
    csr_rowptr_kernel<<<NCHUNK, CHUNK, 0, stream>>>(deg, partial, rowptr, cursor);
    csr_fill_kernel<<<edge_grid, 256, 0, stream>>>(src, dst, cursor, elist);

    // ---- conv1 ----
    gather_agg_kernel<<<gather_grid, 256, 0, stream>>>(x, x, rowptr, elist, B0);
    gemm_mlp_kernel<true, true><<<gemm_grid, 256, 0, stream>>>(
        B0, w1_1, b1_1, bn1g, bn1b, bn1m, bn1v, B1, N_NODES);
    gemm_mlp_kernel<false, true><<<gemm_grid, 256, 0, stream>>>(
        B1, w1_2, b1_2, nullptr, nullptr, nullptr, nullptr, B2, N_NODES);

    // ---- conv2 ----
    gather_agg_kernel<<<gather_grid, 256, 0, stream>>>(B2, B2, rowptr, elist, B0);
    gemm_mlp_kernel<true, true><<<gemm_grid, 256, 0, stream>>>(
        B0, w2_1, b2_1, bn2g, bn2b, bn2m, bn2v, B1, N_NODES);
    gemm_mlp_kernel<false, true><<<gemm_grid, 256, 0, stream>>>(
        B1, w2_2, b2_2, nullptr, nullptr, nullptr, nullptr, B2, N_NODES);

    // ---- pool + head ----
    pool_kernel<<<NUM_GRAPHS, 256, 0, stream>>>(B2, batch, G, N_NODES);
    head1_kernel<<<64, 256, 0, stream>>>(G, lin1w, lin1b, G2);
    head2_kernel<<<1, 256, 0, stream>>>(G2, lin2w, lin2b, (float*)d_out);
}

// Round 4
// 278.493 us; speedup vs baseline: 10.5224x; 1.6359x over previous
//
#include <hip/hip_runtime.h>
#include <hip/hip_bf16.h>

#define N_NODES 50000
#define N_EDGES 800000
#define DIM 128
#define NUM_GRAPHS 128
#define BN_EPS 1e-5f

constexpr int CHUNK  = 512;
constexpr int NCHUNK = (N_NODES + CHUNK - 1) / CHUNK;   // 98

typedef __attribute__((ext_vector_type(8))) short short8;
typedef __attribute__((ext_vector_type(4))) float f32x4;

__device__ __forceinline__ unsigned short f2bu(float v)
{
    __hip_bfloat16 h = __float2bfloat16(v);
    unsigned short u;
    __builtin_memcpy(&u, &h, 2);
    return u;
}
__device__ __forceinline__ float lo2f(unsigned int v)
{
    return __builtin_bit_cast(float, v << 16);
}
__device__ __forceinline__ float hi2f(unsigned int v)
{
    return __builtin_bit_cast(float, v & 0xffff0000u);
}

// ---------------------------------------------------------------------------
// conversions
// ---------------------------------------------------------------------------
__global__ __launch_bounds__(256)
void convert_x_kernel(const float* __restrict__ x, __hip_bfloat16* __restrict__ xb)
{
    size_t i = ((size_t)blockIdx.x * 256 + threadIdx.x) * 4;
    float4 v = *reinterpret_cast<const float4*>(x + i);
    uint2 o;
    o.x = (unsigned int)f2bu(v.x) | ((unsigned int)f2bu(v.y) << 16);
    o.y = (unsigned int)f2bu(v.z) | ((unsigned int)f2bu(v.w) << 16);
    *reinterpret_cast<uint2*>(reinterpret_cast<unsigned short*>(xb) + i) = o;
}

// Wt[m][n][k] = bf16( W_m[k][n] ) for the 4 128x128 weights
__global__ __launch_bounds__(256)
void convert_wt_kernel(const float* __restrict__ w0, const float* __restrict__ w1,
                       const float* __restrict__ w2, const float* __restrict__ w3,
                       __hip_bfloat16* __restrict__ wt)
{
    int o = blockIdx.x * 256 + threadIdx.x;       // 65536
    int m = o >> 14, idx = o & 16383;
    const float* W = (m == 0) ? w0 : (m == 1) ? w1 : (m == 2) ? w2 : w3;
    int n = idx >> 7, k = idx & 127;
    wt[o] = __float2bfloat16(W[k * 128 + n]);
}

// ---------------------------------------------------------------------------
// CSR build
// ---------------------------------------------------------------------------
__global__ __launch_bounds__(256)
void csr_hist_kernel(const int* __restrict__ dst, int* __restrict__ deg)
{
    int e = blockIdx.x * 256 + threadIdx.x;
    if (e < N_EDGES) atomicAdd(&deg[dst[e]], 1);
}

__global__ __launch_bounds__(256)
void csr_partial_kernel(const int* __restrict__ deg, int* __restrict__ partial)
{
    __shared__ int s[256];
    int blk = blockIdx.x;
    int t = threadIdx.x;
    int i0 = blk * CHUNK + t;
    int v = 0;
    if (i0 < N_NODES) v += deg[i0];
    if (i0 + 256 < N_NODES && t + 256 < CHUNK) v += deg[i0 + 256];
    s[t] = v;
    __syncthreads();
    for (int off = 128; off > 0; off >>= 1) {
        if (t < off) s[t] += s[t + off];
        __syncthreads();
    }
    if (t == 0) partial[blk] = s[0];
}

// parallel exclusive scan of the 98 partials
__global__ __launch_bounds__(128)
void csr_scanpart_kernel(int* __restrict__ partial)
{
    __shared__ int s[128];
    int t = threadIdx.x;
    int v = (t < NCHUNK) ? partial[t] : 0;
    s[t] = v;
    __syncthreads();
    for (int off = 1; off < 128; off <<= 1) {
        int add = (t >= off) ? s[t - off] : 0;
        __syncthreads();
        s[t] += add;
        __syncthreads();
    }
    if (t < NCHUNK) partial[t] = s[t] - v;
}

__global__ __launch_bounds__(CHUNK)
void csr_rowptr_kernel(const int* __restrict__ deg,
                       const int* __restrict__ partial,
                       int* __restrict__ rowptr,
                       int* __restrict__ cursor)
{
    __shared__ int s[CHUNK];
    int t = threadIdx.x;
    int i = blockIdx.x * CHUNK + t;
    int v = (i < N_NODES) ? deg[i] : 0;
    s[t] = v;
    __syncthreads();
    for (int off = 1; off < CHUNK; off <<= 1) {
        int add = (t >= off) ? s[t - off] : 0;
        __syncthreads();
        s[t] += add;
        __syncthreads();
    }
    if (i < N_NODES) {
        int excl = partial[blockIdx.x] + s[t] - v;
        rowptr[i] = excl;
        cursor[i] = excl;
    }
    if (blockIdx.x == 0 && t == 0) rowptr[N_NODES] = N_EDGES;
}

__global__ __launch_bounds__(256)
void csr_fill_kernel(const int* __restrict__ src,
                     const int* __restrict__ dst,
                     int* __restrict__ cursor,
                     int* __restrict__ elist)
{
    int e = blockIdx.x * 256 + threadIdx.x;
    if (e < N_EDGES) {
        int idx = atomicAdd(&cursor[dst[e]], 1);
        elist[idx] = src[e];
    }
}

// ---------------------------------------------------------------------------
// gather-aggregate (bf16 feat, f32 accum, bf16 out), fused with GIN self term:
//   out[i] = feat[i] + sum_{j in N(i)} feat[j]
// 4 nodes per 256-thread block; thread owns a channel PAIR (one uint).
// ---------------------------------------------------------------------------
__global__ __launch_bounds__(256)
void gather_agg_kernel(const __hip_bfloat16* __restrict__ feat,
                       const int* __restrict__ rowptr,
                       const int* __restrict__ elist,
                       __hip_bfloat16* __restrict__ out)
{
    int node = blockIdx.x * 4 + (threadIdx.x >> 6);
    int cu   = threadIdx.x & 63;           // uint index within row (2 bf16)
    if (node >= N_NODES) return;
    const unsigned int* F = reinterpret_cast<const unsigned int*>(feat);
    int p = rowptr[node];
    const int e = rowptr[node + 1];
    unsigned int vs = F[(size_t)node * 64 + cu];
    float a0 = lo2f(vs), a1 = hi2f(vs);
    float b0 = 0.f, b1 = 0.f, c0 = 0.f, c1 = 0.f, d0 = 0.f, d1 = 0.f;
    for (; p + 4 <= e; p += 4) {
        int s0 = elist[p], s1 = elist[p + 1], s2 = elist[p + 2], s3 = elist[p + 3];
        unsigned int v0 = F[(size_t)s0 * 64 + cu];
        unsigned int v1 = F[(size_t)s1 * 64 + cu];
        unsigned int v2 = F[(size_t)s2 * 64 + cu];
        unsigned int v3 = F[(size_t)s3 * 64 + cu];
        a0 += lo2f(v0); a1 += hi2f(v0);
        b0 += lo2f(v1); b1 += hi2f(v1);
        c0 += lo2f(v2); c1 += hi2f(v2);
        d0 += lo2f(v3); d1 += hi2f(v3);
    }
    for (; p < e; ++p) {
        unsigned int v0 = F[(size_t)elist[p] * 64 + cu];
        a0 += lo2f(v0); a1 += hi2f(v0);
    }
    float r0 = (a0 + b0) + (c0 + d0);
    float r1 = (a1 + b1) + (c1 + d1);
    reinterpret_cast<unsigned int*>(out)[(size_t)node * 64 + cu] =
        (unsigned int)f2bu(r0) | ((unsigned int)f2bu(r1) << 16);
}

// ---------------------------------------------------------------------------
// Fused GIN MLP: out = relu( relu(BN(A @ W1 + b1)) @ W2 + b2 )
// A: [M][128] bf16. W1t/W2t: [n][k] bf16 (pre-transposed). MFMA 16x16x32.
// Block: 256 thr = 4 waves; 64 rows/block; wave w owns rows w*16..w*16+15,
// all 128 cols (8 col-tiles). W staged in LDS (re-staged for layer 2),
// t1 held in LDS (bf16). Row pad +8 shorts keeps 16B align, 2-way only.
// ---------------------------------------------------------------------------
__global__ __launch_bounds__(256)
void mlp_kernel(const __hip_bfloat16* __restrict__ A,
                const __hip_bfloat16* __restrict__ W1t,
                const __hip_bfloat16* __restrict__ W2t,
                const float* __restrict__ b1,
                const float* __restrict__ bng, const float* __restrict__ bnb,
                const float* __restrict__ bnm, const float* __restrict__ bnv,
                const float* __restrict__ b2,
                __hip_bfloat16* __restrict__ out, int M)
{
    __shared__ __align__(16) short sW[128 * 136];   // 34.8 KB
    __shared__ __align__(16) short sT[64 * 136];    // 17.4 KB

    const int t    = threadIdx.x;
    const int w    = t >> 6;
    const int l    = t & 63;
    const int lr   = l & 15;            // A-row / B-col within tile
    const int lk   = (l >> 4) << 3;     // k offset 0,8,16,24
    const int orow = (l >> 4) << 2;     // C row group 0,4,8,12
    const int row0 = blockIdx.x * 64 + w * 16;

    // stage W1 (16B chunks, 8 per thread)
    const short* w1s = reinterpret_cast<const short*>(W1t);
    #pragma unroll
    for (int i = t; i < 2048; i += 256) {
        int r = i >> 4, c8 = (i & 15) << 3;
        *reinterpret_cast<short8*>(&sW[r * 136 + c8]) =
            *reinterpret_cast<const short8*>(&w1s[r * 128 + c8]);
    }

    // BN scale/shift per owned column (independent of LDS)
    float sc1[8], sh1[8];
    #pragma unroll
    for (int ct = 0; ct < 8; ++ct) {
        int c = ct * 16 + lr;
        float s = bng[c] * rsqrtf(bnv[c] + BN_EPS);
        sc1[ct] = s;
        sh1[ct] = (b1[c] - bnm[c]) * s + bnb[c];
    }

    // A fragments straight from global (each element read exactly once)
    const short* Ab = reinterpret_cast<const short*>(A);
    const int arow = row0 + lr;
    short8 af[4];
    #pragma unroll
    for (int ks = 0; ks < 4; ++ks) {
        short8 z = {};
        af[ks] = (arow < M)
            ? *reinterpret_cast<const short8*>(Ab + (size_t)arow * DIM + ks * 32 + lk)
            : z;
    }

    __syncthreads();

    // GEMM1
    f32x4 acc[8] = {};
    #pragma unroll
    for (int ks = 0; ks < 4; ++ks) {
        #pragma unroll
        for (int ct = 0; ct < 8; ++ct) {
            short8 bf = *reinterpret_cast<const short8*>(
                &sW[(ct * 16 + lr) * 136 + ks * 32 + lk]);
            acc[ct] = __builtin_amdgcn_mfma_f32_16x16x32_bf16(af[ks], bf, acc[ct], 0, 0, 0);
        }
    }

    // epilogue1: BN + ReLU -> sT (bf16). D layout: row=(l>>4)*4+q, col=lr.
    #pragma unroll
    for (int ct = 0; ct < 8; ++ct) {
        #pragma unroll
        for (int q = 0; q < 4; ++q) {
            float v = fmaxf(acc[ct][q] * sc1[ct] + sh1[ct], 0.f);
            sT[(w * 16 + orow + q) * 136 + ct * 16 + lr] = (short)f2bu(v);
        }
    }

    __syncthreads();            // all waves done with sW (GEMM1)
    // stage W2 over sW
    const short* w2s = reinterpret_cast<const short*>(W2t);
    #pragma unroll
    for (int i = t; i < 2048; i += 256) {
        int r = i >> 4, c8 = (i & 15) << 3;
        *reinterpret_cast<short8*>(&sW[r * 136 + c8]) =
            *reinterpret_cast<const short8*>(&w2s[r * 128 + c8]);
    }
    __syncthreads();

    // GEMM2
    f32x4 acc2[8] = {};
    #pragma unroll
    for (int ks = 0; ks < 4; ++ks) {
        short8 tf = *reinterpret_cast<const short8*>(
            &sT[(w * 16 + lr) * 136 + ks * 32 + lk]);
        #pragma unroll
        for (int ct = 0; ct < 8; ++ct) {
            short8 bf = *reinterpret_cast<const short8*>(
                &sW[(ct * 16 + lr) * 136 + ks * 32 + lk]);
            acc2[ct] = __builtin_amdgcn_mfma_f32_16x16x32_bf16(tf, bf, acc2[ct], 0, 0, 0);
        }
    }

    // epilogue2: bias + ReLU -> global bf16
    #pragma unroll
    for (int ct = 0; ct < 8; ++ct) {
        float bi = b2[ct * 16 + lr];
        #pragma unroll
        for (int q = 0; q < 4; ++q) {
            int r = row0 + orow + q;
            if (r < M) {
                float v = fmaxf(acc2[ct][q] + bi, 0.f);
                out[(size_t)r * DIM + ct * 16 + lr] = __float2bfloat16(v);
            }
        }
    }
}

// ---------------------------------------------------------------------------
// global_add_pool over sorted batch ids (bf16 in, f32 out)
// ---------------------------------------------------------------------------
__global__ __launch_bounds__(256)
void pool_kernel(const __hip_bfloat16* __restrict__ h,
                 const int* __restrict__ batch,
                 float* __restrict__ G,
                 int n_nodes)
{
    const int g = blockIdx.x;
    int lo = 0, hi = n_nodes;
    while (lo < hi) { int mid = (lo + hi) >> 1; if (batch[mid] < g) lo = mid + 1; else hi = mid; }
    const int start = lo;
    hi = n_nodes;
    while (lo < hi) { int mid = (lo + hi) >> 1; if (batch[mid] < g + 1) lo = mid + 1; else hi = mid; }
    const int end = lo;

    const int t  = threadIdx.x;
    const int cu = t & 63;
    const int rp = t >> 6;
    const unsigned int* F = reinterpret_cast<const unsigned int*>(h);
    float a0 = 0.f, a1 = 0.f;
    for (int r = start + rp; r < end; r += 4) {
        unsigned int v = F[(size_t)r * 64 + cu];
        a0 += lo2f(v); a1 += hi2f(v);
    }
    __shared__ float s0[256], s1[256];
    s0[t] = a0; s1[t] = a1;
    __syncthreads();
    if (t < 64) {
        float r0 = s0[t] + s0[t + 64] + s0[t + 128] + s0[t + 192];
        float r1 = s1[t] + s1[t + 64] + s1[t + 128] + s1[t + 192];
        G[g * DIM + cu * 2]     = r0;
        G[g * DIM + cu * 2 + 1] = r1;
    }
}

// ---------------------------------------------------------------------------
// head (tiny, f32)
// ---------------------------------------------------------------------------
__global__ __launch_bounds__(256)
void head1_kernel(const float* __restrict__ G,
                  const float* __restrict__ W,
                  const float* __restrict__ b,
                  float* __restrict__ G2)
{
    int o = blockIdx.x * 256 + threadIdx.x;
    int r = o >> 7, c = o & 127;
    float acc = b[c];
    #pragma unroll 4
    for (int k = 0; k < DIM; ++k)
        acc = fmaf(G[r * DIM + k], W[k * DIM + c], acc);
    G2[o] = fmaxf(acc, 0.f);
}

__global__ __launch_bounds__(256)
void head2_kernel(const float* __restrict__ G2,
                  const float* __restrict__ W,
                  const float* __restrict__ b,
                  float* __restrict__ out)
{
    int o = threadIdx.x;
    int r = o >> 1, c = o & 1;
    float acc = b[c];
    #pragma unroll 4
    for (int k = 0; k < DIM; ++k)
        acc = fmaf(G2[r * DIM + k], W[k * 2 + c], acc);
    out[o] = acc;
}

// ---------------------------------------------------------------------------
extern "C" void kernel_launch(void* const* d_in, const int* in_sizes, int n_in,
                              void* d_out, int out_size, void* d_ws, size_t ws_size,
                              hipStream_t stream)
{
    const float* x    = (const float*)d_in[0];
    const int*   ei   = (const int*)d_in[1];
    const int*   src  = ei;
    const int*   dst  = ei + N_EDGES;
    const int*   batch= (const int*)d_in[2];
    const float* w1_1 = (const float*)d_in[3];
    const float* b1_1 = (const float*)d_in[4];
    const float* bn1g = (const float*)d_in[5];
    const float* bn1b = (const float*)d_in[6];
    const float* bn1m = (const float*)d_in[7];
    const float* bn1v = (const float*)d_in[8];
    const float* w1_2 = (const float*)d_in[9];
    const float* b1_2 = (const float*)d_in[10];
    const float* w2_1 = (const float*)d_in[11];
    const float* b2_1 = (const float*)d_in[12];
    const float* bn2g = (const float*)d_in[13];
    const float* bn2b = (const float*)d_in[14];
    const float* bn2m = (const float*)d_in[15];
    const float* bn2v = (const float*)d_in[16];
    const float* w2_2 = (const float*)d_in[17];
    const float* b2_2 = (const float*)d_in[18];
    const float* lin1w= (const float*)d_in[19];
    const float* lin1b= (const float*)d_in[20];
    const float* lin2w= (const float*)d_in[21];
    const float* lin2b= (const float*)d_in[22];

    const size_t NBE = (size_t)N_NODES * DIM;      // 6.4M
    __hip_bfloat16* xb = (__hip_bfloat16*)d_ws;    // NBE bf16
    __hip_bfloat16* Ab = xb + NBE;                 // NBE bf16 (agg)
    __hip_bfloat16* Hb = Ab + NBE;                 // NBE bf16 (mlp out)
    __hip_bfloat16* Wt = Hb + NBE;                 // 4 * 16384 bf16
    float* G  = (float*)(Wt + 4 * 16384);
    float* G2 = G + NUM_GRAPHS * DIM;
    int* deg    = (int*)(G2 + NUM_GRAPHS * DIM);
    int* rowptr = deg + N_NODES;                   // N_NODES+1
    int* cursor = rowptr + N_NODES + 1;
    int* partial= cursor + N_NODES;                // NCHUNK
    int* elist  = partial + NCHUNK + 2;            // N_EDGES

    const int edge_grid   = (N_EDGES + 255) / 256;     // 3125
    const int gather_grid = N_NODES / 4;               // 12500
    const int mlp_grid    = (N_NODES + 63) / 64;       // 782

    // ---- conversions + CSR build ----
    convert_x_kernel<<<(int)(NBE / 1024), 256, 0, stream>>>(x, xb);
    convert_wt_kernel<<<256, 256, 0, stream>>>(w1_1, w1_2, w2_1, w2_2, Wt);
    hipMemsetAsync(deg, 0, N_NODES * sizeof(int), stream);
    csr_hist_kernel<<<edge_grid, 256, 0, stream>>>(dst, deg);
    csr_partial_kernel<<<NCHUNK, 256, 0, stream>>>(deg, partial);
    csr_scanpart_kernel<<<1, 128, 0, stream>>>(partial);
    csr_rowptr_kernel<<<NCHUNK, CHUNK, 0, stream>>>(deg, partial, rowptr, cursor);
    csr_fill_kernel<<<edge_grid, 256, 0, stream>>>(src, dst, cursor, elist);

    // ---- conv1 ----
    gather_agg_kernel<<<gather_grid, 256, 0, stream>>>(xb, rowptr, elist, Ab);
    mlp_kernel<<<mlp_grid, 256, 0, stream>>>(
        Ab, Wt, Wt + 16384, b1_1, bn1g, bn1b, bn1m, bn1v, b1_2, Hb, N_NODES);

    // ---- conv2 ----
    gather_agg_kernel<<<gather_grid, 256, 0, stream>>>(Hb, rowptr, elist, Ab);
    mlp_kernel<<<mlp_grid, 256, 0, stream>>>(
        Ab, Wt + 2 * 16384, Wt + 3 * 16384, b2_1, bn2g, bn2b, bn2m, bn2v, b2_2, Hb, N_NODES);

    // ---- pool + head ----
    pool_kernel<<<NUM_GRAPHS, 256, 0, stream>>>(Hb, batch, G, N_NODES);
    head1_kernel<<<64, 256, 0, stream>>>(G, lin1w, lin1b, G2);
    head2_kernel<<<1, 256, 0, stream>>>(G2, lin2w, lin2b, (float*)d_out);
}

// Round 6
// 222.806 us; speedup vs baseline: 13.1523x; 1.2499x over previous
//
#include <hip/hip_runtime.h>
#include <hip/hip_bf16.h>

#define N_NODES 50000
#define N_EDGES 800000
#define DIM 128
#define NUM_GRAPHS 128
#define BN_EPS 1e-5f

constexpr int BK     = 7;                               // nodes-per-bucket log2
constexpr int NBUCK  = (N_NODES + 127) >> BK;           // 391
constexpr int TILE   = 4096;                            // edges per bscatter block
constexpr int NTILE  = (N_EDGES + TILE - 1) / TILE;     // 196

typedef __attribute__((ext_vector_type(8))) short short8;
typedef __attribute__((ext_vector_type(4))) float f32x4;

__device__ __forceinline__ unsigned short f2bu(float v)
{
    __hip_bfloat16 h = __float2bfloat16(v);
    unsigned short u;
    __builtin_memcpy(&u, &h, 2);
    return u;
}
__device__ __forceinline__ float lo2f(unsigned int v)
{
    return __builtin_bit_cast(float, v << 16);
}
__device__ __forceinline__ float hi2f(unsigned int v)
{
    return __builtin_bit_cast(float, v & 0xffff0000u);
}

// ---------------------------------------------------------------------------
// conversions
// ---------------------------------------------------------------------------
__global__ __launch_bounds__(256)
void convert_x_kernel(const float* __restrict__ x, __hip_bfloat16* __restrict__ xb)
{
    size_t i = ((size_t)blockIdx.x * 256 + threadIdx.x) * 4;
    float4 v = *reinterpret_cast<const float4*>(x + i);
    uint2 o;
    o.x = (unsigned int)f2bu(v.x) | ((unsigned int)f2bu(v.y) << 16);
    o.y = (unsigned int)f2bu(v.z) | ((unsigned int)f2bu(v.w) << 16);
    *reinterpret_cast<uint2*>(reinterpret_cast<unsigned short*>(xb) + i) = o;
}

// Wt[m][n][k] = bf16( W_m[k][n] ) for the 4 128x128 weights
__global__ __launch_bounds__(256)
void convert_wt_kernel(const float* __restrict__ w0, const float* __restrict__ w1,
                       const float* __restrict__ w2, const float* __restrict__ w3,
                       __hip_bfloat16* __restrict__ wt)
{
    int o = blockIdx.x * 256 + threadIdx.x;       // 65536
    int m = o >> 14, idx = o & 16383;
    const float* W = (m == 0) ? w0 : (m == 1) ? w1 : (m == 2) ? w2 : w3;
    int n = idx >> 7, k = idx & 127;
    wt[o] = __float2bfloat16(W[k * 128 + n]);
}

// ---------------------------------------------------------------------------
// Bucketed CSR build. Bucket = dst >> 7 (128 nodes / bucket, 391 buckets).
// Every global write region has a single writer block -> no cross-XCD
// partial-line writeback amplification (round-4: csr_fill wrote 52MB).
// ---------------------------------------------------------------------------

// 1) bucket histogram: per-block LDS hist + merge
__global__ __launch_bounds__(256)
void bhist_kernel(const int* __restrict__ dst, int* __restrict__ bhist)
{
    __shared__ int h[NBUCK];
    int t = threadIdx.x;
    for (int i = t; i < NBUCK; i += 256) h[i] = 0;
    __syncthreads();
    int e0 = blockIdx.x * TILE;
    for (int i = t; i < TILE; i += 256) {
        int e = e0 + i;
        if (e < N_EDGES) atomicAdd(&h[dst[e] >> BK], 1);
    }
    __syncthreads();
    for (int i = t; i < NBUCK; i += 256)
        if (h[i]) atomicAdd(&bhist[i], h[i]);
}

// 2) scan bucket counts -> offsets + cursor init (one block)
__global__ __launch_bounds__(512)
void bscan_kernel(const int* __restrict__ bhist,
                  int* __restrict__ bofs, int* __restrict__ bcur)
{
    __shared__ int s[512];
    int t = threadIdx.x;
    int v = (t < NBUCK) ? bhist[t] : 0;
    s[t] = v;
    __syncthreads();
    for (int o = 1; o < 512; o <<= 1) {
        int a = (t >= o) ? s[t - o] : 0;
        __syncthreads();
        s[t] += a;
        __syncthreads();
    }
    if (t < NBUCK) {
        int ex = s[t] - v;
        bofs[t] = ex;
        bcur[t] = ex;
    }
    if (t == 0) bofs[NBUCK] = N_EDGES;
}

// 3) bucket scatter: tile -> LDS grouped by bucket -> coalesced emit.
//    packed edge word: src(16) | dstlow(7)<<16 | bucket(9)<<23
__global__ __launch_bounds__(512)
void bscatter_kernel(const int* __restrict__ src, const int* __restrict__ dst,
                     int* __restrict__ bcur, unsigned int* __restrict__ bedge)
{
    __shared__ int h[512];
    __shared__ int s[512];
    __shared__ int lofs[512];
    __shared__ int cur[512];
    __shared__ int gbase[512];
    __shared__ unsigned int stage[TILE];

    int t = threadIdx.x;
    h[t] = 0;
    __syncthreads();

    int e0 = blockIdx.x * TILE;
    for (int i = t; i < TILE; i += 512) {
        int e = e0 + i;
        if (e < N_EDGES) atomicAdd(&h[dst[e] >> BK], 1);
    }
    __syncthreads();

    int v = h[t];
    s[t] = v;
    __syncthreads();
    for (int o = 1; o < 512; o <<= 1) {
        int a = (t >= o) ? s[t - o] : 0;
        __syncthreads();
        s[t] += a;
        __syncthreads();
    }
    int excl = s[t] - v;
    lofs[t] = excl;
    cur[t]  = excl;
    if (t < NBUCK)
        gbase[t] = v ? atomicAdd(&bcur[t], v) : 0;
    __syncthreads();

    const int mtot = s[511];          // valid edges in this tile

    for (int i = t; i < TILE; i += 512) {
        int e = e0 + i;
        if (e < N_EDGES) {
            int d = dst[e];
            int b = d >> BK;
            int r = atomicAdd(&cur[b], 1);
            stage[r] = (unsigned int)src[e]
                     | ((unsigned int)(d & 127) << 16)
                     | ((unsigned int)b << 23);
        }
    }
    __syncthreads();

    for (int i = t; i < mtot; i += 512) {
        unsigned int w = stage[i];
        int b = (int)(w >> 23);
        bedge[gbase[b] + (i - lofs[b])] = w & 0x7fffffu;
    }
}

// 4) per-bucket CSR finalize: rowptr + ushort elist, all writes block-private
__global__ __launch_bounds__(256)
void bcsr_kernel(const unsigned int* __restrict__ bedge,
                 const int* __restrict__ bofs,
                 int* __restrict__ rowptr,
                 unsigned short* __restrict__ elist)
{
    __shared__ int h2[128];
    __shared__ int sc[128];
    __shared__ int cur[128];

    int b  = blockIdx.x;
    int t  = threadIdx.x;
    int e0 = bofs[b], e1 = bofs[b + 1];
    int m  = e1 - e0;

    if (t < 128) h2[t] = 0;
    __syncthreads();
    for (int i = t; i < m; i += 256)
        atomicAdd(&h2[(bedge[e0 + i] >> 16) & 127], 1);
    __syncthreads();

    if (t < 128) sc[t] = h2[t];
    __syncthreads();
    for (int o = 1; o < 128; o <<= 1) {
        int a = 0;
        if (t < 128 && t >= o) a = sc[t - o];
        __syncthreads();
        if (t < 128) sc[t] += a;
        __syncthreads();
    }
    if (t < 128) {
        int ex = sc[t] - h2[t];
        int node = (b << BK) + t;
        if (node < N_NODES) rowptr[node] = e0 + ex;
        cur[t] = ex;
    }
    if (b == 0 && t == 0) rowptr[N_NODES] = N_EDGES;
    __syncthreads();

    for (int i = t; i < m; i += 256) {
        unsigned int w = bedge[e0 + i];
        int n = (int)((w >> 16) & 127);
        int r = atomicAdd(&cur[n], 1);
        elist[e0 + r] = (unsigned short)(w & 0xffffu);
    }
}

// ---------------------------------------------------------------------------
// gather-aggregate (bf16 feat, f32 accum, bf16 out), fused with GIN self term:
//   out[i] = feat[i] + sum_{j in N(i)} feat[j]
// 4 nodes per 256-thread block; thread owns a channel PAIR (one uint).
// ---------------------------------------------------------------------------
__global__ __launch_bounds__(256)
void gather_agg_kernel(const __hip_bfloat16* __restrict__ feat,
                       const int* __restrict__ rowptr,
                       const unsigned short* __restrict__ elist,
                       __hip_bfloat16* __restrict__ out)
{
    int node = blockIdx.x * 4 + (threadIdx.x >> 6);
    int cu   = threadIdx.x & 63;           // uint index within row (2 bf16)
    if (node >= N_NODES) return;
    const unsigned int* F = reinterpret_cast<const unsigned int*>(feat);
    int p = rowptr[node];
    const int e = rowptr[node + 1];
    unsigned int vs = F[(size_t)node * 64 + cu];
    float a0 = lo2f(vs), a1 = hi2f(vs);
    float b0 = 0.f, b1 = 0.f, c0 = 0.f, c1 = 0.f, d0 = 0.f, d1 = 0.f;
    for (; p + 4 <= e; p += 4) {
        int s0 = elist[p], s1 = elist[p + 1], s2 = elist[p + 2], s3 = elist[p + 3];
        unsigned int v0 = F[(size_t)s0 * 64 + cu];
        unsigned int v1 = F[(size_t)s1 * 64 + cu];
        unsigned int v2 = F[(size_t)s2 * 64 + cu];
        unsigned int v3 = F[(size_t)s3 * 64 + cu];
        a0 += lo2f(v0); a1 += hi2f(v0);
        b0 += lo2f(v1); b1 += hi2f(v1);
        c0 += lo2f(v2); c1 += hi2f(v2);
        d0 += lo2f(v3); d1 += hi2f(v3);
    }
    for (; p < e; ++p) {
        unsigned int v0 = F[(size_t)elist[p] * 64 + cu];
        a0 += lo2f(v0); a1 += hi2f(v0);
    }
    float r0 = (a0 + b0) + (c0 + d0);
    float r1 = (a1 + b1) + (c1 + d1);
    reinterpret_cast<unsigned int*>(out)[(size_t)node * 64 + cu] =
        (unsigned int)f2bu(r0) | ((unsigned int)f2bu(r1) << 16);
}

// ---------------------------------------------------------------------------
// Fused GIN MLP: out = relu( relu(BN(A @ W1 + b1)) @ W2 + b2 )
// MFMA 16x16x32, W in LDS, t1 in LDS
// ---------------------------------------------------------------------------
__global__ __launch_bounds__(256)
void mlp_kernel(const __hip_bfloat16* __restrict__ A,
                const __hip_bfloat16* __restrict__ W1t,
                const __hip_bfloat16* __restrict__ W2t,
                const float* __restrict__ b1,
                const float* __restrict__ bng, const float* __restrict__ bnb,
                const float* __restrict__ bnm, const float* __restrict__ bnv,
                const float* __restrict__ b2,
                __hip_bfloat16* __restrict__ out, int M)
{
    __shared__ __align__(16) short sW[128 * 136];   // 34.8 KB
    __shared__ __align__(16) short sT[64 * 136];    // 17.4 KB

    const int t    = threadIdx.x;
    const int w    = t >> 6;
    const int l    = t & 63;
    const int lr   = l & 15;
    const int lk   = (l >> 4) << 3;
    const int orow = (l >> 4) << 2;
    const int row0 = blockIdx.x * 64 + w * 16;

    const short* w1s = reinterpret_cast<const short*>(W1t);
    #pragma unroll
    for (int i = t; i < 2048; i += 256) {
        int r = i >> 4, c8 = (i & 15) << 3;
        *reinterpret_cast<short8*>(&sW[r * 136 + c8]) =
            *reinterpret_cast<const short8*>(&w1s[r * 128 + c8]);
    }

    float sc1[8], sh1[8];
    #pragma unroll
    for (int ct = 0; ct < 8; ++ct) {
        int c = ct * 16 + lr;
        float s = bng[c] * rsqrtf(bnv[c] + BN_EPS);
        sc1[ct] = s;
        sh1[ct] = (b1[c] - bnm[c]) * s + bnb[c];
    }

    const short* Ab = reinterpret_cast<const short*>(A);
    const int arow = row0 + lr;
    short8 af[4];
    #pragma unroll
    for (int ks = 0; ks < 4; ++ks) {
        short8 z = {};
        af[ks] = (arow < M)
            ? *reinterpret_cast<const short8*>(Ab + (size_t)arow * DIM + ks * 32 + lk)
            : z;
    }

    __syncthreads();

    f32x4 acc[8] = {};
    #pragma unroll
    for (int ks = 0; ks < 4; ++ks) {
        #pragma unroll
        for (int ct = 0; ct < 8; ++ct) {
            short8 bf = *reinterpret_cast<const short8*>(
                &sW[(ct * 16 + lr) * 136 + ks * 32 + lk]);
            acc[ct] = __builtin_amdgcn_mfma_f32_16x16x32_bf16(af[ks], bf, acc[ct], 0, 0, 0);
        }
    }

    #pragma unroll
    for (int ct = 0; ct < 8; ++ct) {
        #pragma unroll
        for (int q = 0; q < 4; ++q) {
            float v = fmaxf(acc[ct][q] * sc1[ct] + sh1[ct], 0.f);
            sT[(w * 16 + orow + q) * 136 + ct * 16 + lr] = (short)f2bu(v);
        }
    }

    __syncthreads();
    const short* w2s = reinterpret_cast<const short*>(W2t);
    #pragma unroll
    for (int i = t; i < 2048; i += 256) {
        int r = i >> 4, c8 = (i & 15) << 3;
        *reinterpret_cast<short8*>(&sW[r * 136 + c8]) =
            *reinterpret_cast<const short8*>(&w2s[r * 128 + c8]);
    }
    __syncthreads();

    f32x4 acc2[8] = {};
    #pragma unroll
    for (int ks = 0; ks < 4; ++ks) {
        short8 tf = *reinterpret_cast<const short8*>(
            &sT[(w * 16 + lr) * 136 + ks * 32 + lk]);
        #pragma unroll
        for (int ct = 0; ct < 8; ++ct) {
            short8 bf = *reinterpret_cast<const short8*>(
                &sW[(ct * 16 + lr) * 136 + ks * 32 + lk]);
            acc2[ct] = __builtin_amdgcn_mfma_f32_16x16x32_bf16(tf, bf, acc2[ct], 0, 0, 0);
        }
    }

    #pragma unroll
    for (int ct = 0; ct < 8; ++ct) {
        float bi = b2[ct * 16 + lr];
        #pragma unroll
        for (int q = 0; q < 4; ++q) {
            int r = row0 + orow + q;
            if (r < M) {
                float v = fmaxf(acc2[ct][q] + bi, 0.f);
                out[(size_t)r * DIM + ct * 16 + lr] = __float2bfloat16(v);
            }
        }
    }
}

// ---------------------------------------------------------------------------
// global_add_pool over sorted batch ids (bf16 in, f32 out)
// ---------------------------------------------------------------------------
__global__ __launch_bounds__(256)
void pool_kernel(const __hip_bfloat16* __restrict__ h,
                 const int* __restrict__ batch,
                 float* __restrict__ G,
                 int n_nodes)
{
    const int g = blockIdx.x;
    int lo = 0, hi = n_nodes;
    while (lo < hi) { int mid = (lo + hi) >> 1; if (batch[mid] < g) lo = mid + 1; else hi = mid; }
    const int start = lo;
    hi = n_nodes;
    while (lo < hi) { int mid = (lo + hi) >> 1; if (batch[mid] < g + 1) lo = mid + 1; else hi = mid; }
    const int end = lo;

    const int t  = threadIdx.x;
    const int cu = t & 63;
    const int rp = t >> 6;
    const unsigned int* F = reinterpret_cast<const unsigned int*>(h);
    float a0 = 0.f, a1 = 0.f;
    for (int r = start + rp; r < end; r += 4) {
        unsigned int v = F[(size_t)r * 64 + cu];
        a0 += lo2f(v); a1 += hi2f(v);
    }
    __shared__ float s0[256], s1[256];
    s0[t] = a0; s1[t] = a1;
    __syncthreads();
    if (t < 64) {
        float r0 = s0[t] + s0[t + 64] + s0[t + 128] + s0[t + 192];
        float r1 = s1[t] + s1[t + 64] + s1[t + 128] + s1[t + 192];
        G[g * DIM + cu * 2]     = r0;
        G[g * DIM + cu * 2 + 1] = r1;
    }
}

// ---------------------------------------------------------------------------
// head (tiny, f32)
// ---------------------------------------------------------------------------
__global__ __launch_bounds__(256)
void head1_kernel(const float* __restrict__ G,
                  const float* __restrict__ W,
                  const float* __restrict__ b,
                  float* __restrict__ G2)
{
    int o = blockIdx.x * 256 + threadIdx.x;
    int r = o >> 7, c = o & 127;
    float acc = b[c];
    #pragma unroll 4
    for (int k = 0; k < DIM; ++k)
        acc = fmaf(G[r * DIM + k], W[k * DIM + c], acc);
    G2[o] = fmaxf(acc, 0.f);
}

__global__ __launch_bounds__(256)
void head2_kernel(const float* __restrict__ G2,
                  const float* __restrict__ W,
                  const float* __restrict__ b,
                  float* __restrict__ out)
{
    int o = threadIdx.x;
    int r = o >> 1, c = o & 1;
    float acc = b[c];
    #pragma unroll 4
    for (int k = 0; k < DIM; ++k)
        acc = fmaf(G2[r * DIM + k], W[k * 2 + c], acc);
    out[o] = acc;
}

// ---------------------------------------------------------------------------
extern "C" void kernel_launch(void* const* d_in, const int* in_sizes, int n_in,
                              void* d_out, int out_size, void* d_ws, size_t ws_size,
                              hipStream_t stream)
{
    const float* x    = (const float*)d_in[0];
    const int*   ei   = (const int*)d_in[1];
    const int*   src  = ei;
    const int*   dst  = ei + N_EDGES;
    const int*   batch= (const int*)d_in[2];
    const float* w1_1 = (const float*)d_in[3];
    const float* b1_1 = (const float*)d_in[4];
    const float* bn1g = (const float*)d_in[5];
    const float* bn1b = (const float*)d_in[6];
    const float* bn1m = (const float*)d_in[7];
    const float* bn1v = (const float*)d_in[8];
    const float* w1_2 = (const float*)d_in[9];
    const float* b1_2 = (const float*)d_in[10];
    const float* w2_1 = (const float*)d_in[11];
    const float* b2_1 = (const float*)d_in[12];
    const float* bn2g = (const float*)d_in[13];
    const float* bn2b = (const float*)d_in[14];
    const float* bn2m = (const float*)d_in[15];
    const float* bn2v = (const float*)d_in[16];
    const float* w2_2 = (const float*)d_in[17];
    const float* b2_2 = (const float*)d_in[18];
    const float* lin1w= (const float*)d_in[19];
    const float* lin1b= (const float*)d_in[20];
    const float* lin2w= (const float*)d_in[21];
    const float* lin2b= (const float*)d_in[22];

    const size_t NBE = (size_t)N_NODES * DIM;      // 6.4M
    __hip_bfloat16* xb = (__hip_bfloat16*)d_ws;    // NBE bf16
    __hip_bfloat16* Ab = xb + NBE;                 // NBE bf16 (agg)
    __hip_bfloat16* Hb = Ab + NBE;                 // NBE bf16 (mlp out)
    __hip_bfloat16* Wt = Hb + NBE;                 // 4 * 16384 bf16
    float* G  = (float*)(Wt + 4 * 16384);
    float* G2 = G + NUM_GRAPHS * DIM;
    int* rowptr = (int*)(G2 + NUM_GRAPHS * DIM);   // N_NODES+1
    int* bhist  = rowptr + N_NODES + 2;            // NBUCK
    int* bofs   = bhist + NBUCK;                   // NBUCK+1
    int* bcur   = bofs + NBUCK + 1;                // NBUCK
    unsigned int* bedge = (unsigned int*)(bcur + NBUCK + 1);     // N_EDGES
    unsigned short* elist = (unsigned short*)(bedge + N_EDGES);  // N_EDGES

    const int gather_grid = N_NODES / 4;               // 12500
    const int mlp_grid    = (N_NODES + 63) / 64;       // 782

    // ---- conversions + bucketed CSR build ----
    convert_x_kernel<<<(int)(NBE / 1024), 256, 0, stream>>>(x, xb);
    convert_wt_kernel<<<256, 256, 0, stream>>>(w1_1, w1_2, w2_1, w2_2, Wt);
    hipMemsetAsync(bhist, 0, NBUCK * sizeof(int), stream);
    bhist_kernel<<<NTILE, 256, 0, stream>>>(dst, bhist);
    bscan_kernel<<<1, 512, 0, stream>>>(bhist, bofs, bcur);
    bscatter_kernel<<<NTILE, 512, 0, stream>>>(src, dst, bcur, bedge);
    bcsr_kernel<<<NBUCK, 256, 0, stream>>>(bedge, bofs, rowptr, elist);

    // ---- conv1 ----
    gather_agg_kernel<<<gather_grid, 256, 0, stream>>>(xb, rowptr, elist, Ab);
    mlp_kernel<<<mlp_grid, 256, 0, stream>>>(
        Ab, Wt, Wt + 16384, b1_1, bn1g, bn1b, bn1m, bn1v, b1_2, Hb, N_NODES);

    // ---- conv2 ----
    gather_agg_kernel<<<gather_grid, 256, 0, stream>>>(Hb, rowptr, elist, Ab);
    mlp_kernel<<<mlp_grid, 256, 0, stream>>>(
        Ab, Wt + 2 * 16384, Wt + 3 * 16384, b2_1, bn2g, bn2b, bn2m, bn2v, b2_2, Hb, N_NODES);

    // ---- pool + head ----
    pool_kernel<<<NUM_GRAPHS, 256, 0, stream>>>(Hb, batch, G, N_NODES);
    head1_kernel<<<64, 256, 0, stream>>>(G, lin1w, lin1b, G2);
    head2_kernel<<<1, 256, 0, stream>>>(G2, lin2w, lin2b, (float*)d_out);
}